// Round 1
// baseline (80376.062 us; speedup 1.0000x reference)
//
#include <hip/hip_runtime.h>
#include <cstddef>

#define B_SZ   16
#define T_SZ   4096
#define D_SZ   512
#define NSLOT  64
#define TSTRIDE 516            // tape row stride (floats): breaks 512-stride bank conflicts, 16B aligned
#define SCALE  0.044194173824159216f   // 1/sqrt(512)

// ---------------------------------------------------------------------------
// Kernel 1: xw[b][t][d] = sum_k x[b][t][k] * W_x[d][k] + b_h[d]
// Written into the h_work_out region of d_out; recurrence kernel reads
// position (b,t) then overwrites it with h_new (safe: step t reads before write).
// Classic 64x64 tile, BK=16, 256 threads, 4x4 micro-tile, fp32.
// ---------------------------------------------------------------------------
__global__ __launch_bounds__(256)
void xw_gemm_kernel(const float* __restrict__ X, const float* __restrict__ Wx,
                    const float* __restrict__ bh, float* __restrict__ out)
{
    __shared__ float As[16][68];   // [kk][m] (+4 pad)
    __shared__ float Bs[16][68];   // [kk][n]
    const int m0 = blockIdx.x * 64;
    const int n0 = blockIdx.y * 64;
    const int tid = threadIdx.x;
    const int tr = tid >> 4, tc = tid & 15;
    const int lrow = tid >> 2;
    const int lkk  = (tid & 3) * 4;

    float acc[4][4] = {};

    for (int k0 = 0; k0 < D_SZ; k0 += 16) {
        float4 av = *(const float4*)(X  + (size_t)(m0 + lrow) * D_SZ + k0 + lkk);
        float4 bv = *(const float4*)(Wx + (size_t)(n0 + lrow) * D_SZ + k0 + lkk);
        As[lkk+0][lrow] = av.x; As[lkk+1][lrow] = av.y;
        As[lkk+2][lrow] = av.z; As[lkk+3][lrow] = av.w;
        Bs[lkk+0][lrow] = bv.x; Bs[lkk+1][lrow] = bv.y;
        Bs[lkk+2][lrow] = bv.z; Bs[lkk+3][lrow] = bv.w;
        __syncthreads();
        #pragma unroll
        for (int kk = 0; kk < 16; ++kk) {
            float a[4], b[4];
            #pragma unroll
            for (int i = 0; i < 4; ++i) a[i] = As[kk][tr*4+i];
            #pragma unroll
            for (int j = 0; j < 4; ++j) b[j] = Bs[kk][tc*4+j];
            #pragma unroll
            for (int i = 0; i < 4; ++i)
                #pragma unroll
                for (int j = 0; j < 4; ++j)
                    acc[i][j] = fmaf(a[i], b[j], acc[i][j]);
        }
        __syncthreads();
    }
    #pragma unroll
    for (int i = 0; i < 4; ++i) {
        const int m = m0 + tr*4 + i;
        const int n = n0 + tc*4;
        float4 o;
        o.x = acc[i][0] + bh[n+0];
        o.y = acc[i][1] + bh[n+1];
        o.z = acc[i][2] + bh[n+2];
        o.w = acc[i][3] + bh[n+3];
        *(float4*)(out + (size_t)m * D_SZ + n) = o;
    }
}

// ---------------------------------------------------------------------------
// Kernel 2: the serial recurrence. One workgroup per batch (16 WGs, 1024 thr).
// Tape in LDS (stride-padded). Weights streamed from L2 each step.
// Per step:
//   ph1: scores[s] = scale * dot(tape[s], h)        (16 threads/slot, shfl reduce)
//   ph2: softmax over 64 slots (wave 0)
//   ph3: read partials rp[g][d] = sum_{s in half g} attn[s]*tape[s][d]
//   ph4: zm[d] = W_h[d,:] . h                       (wave-per-4-rows, coalesced)
//   ph5: h_new = tanh(zm + rp0 + rp1 + xw) ; store to out, LDS
//   ph6: tape[t%64][d] = W_write[d,:] . h_new
// ---------------------------------------------------------------------------
__global__ __launch_bounds__(1024, 1)
void recurrence_kernel(const float* __restrict__ tape0,   // [B][64][512]
                       const float* __restrict__ h0,      // [B][512]
                       const float* __restrict__ W_h,     // [512][512]
                       const float* __restrict__ W_w,     // [512][512]
                       float* __restrict__ out)           // flat outputs
{
    __shared__ float tape[NSLOT * TSTRIDE];   // 132,096 B
    __shared__ float hbuf[2][D_SZ];
    __shared__ float zm[D_SZ];
    __shared__ float rp[2][D_SZ];
    __shared__ float scores[NSLOT];
    __shared__ float attn[NSLOT];

    const int b    = blockIdx.x;
    const int tid  = threadIdx.x;
    const int lane = tid & 63;
    const int wave = tid >> 6;
    const int sj   = tid & 15;      // k-lane within a 16-lane group
    const int ss   = tid >> 4;      // slot index for phase 1 (0..63)
    const int r4   = (lane >> 4);   // row-within-quad for matvec phases

    // ---- init: stage tape + h into LDS ----
    for (int i = tid; i < NSLOT * D_SZ; i += 1024) {
        const int s = i >> 9, d = i & 511;
        tape[s * TSTRIDE + d] = tape0[(size_t)(b * NSLOT + s) * D_SZ + d];
    }
    if (tid < D_SZ) hbuf[0][tid] = h0[(size_t)b * D_SZ + tid];
    __syncthreads();

    float* outb = out + (size_t)b * T_SZ * D_SZ;
    int cur = 0;

    for (int t = 0; t < T_SZ; ++t) {
        const float* h  = hbuf[cur];
        float*       hn = hbuf[cur ^ 1];

        // ---- phase 1: scores ----
        // also preload this thread's h chunk into registers (reused in phase 4)
        float4 hreg[8];
        #pragma unroll
        for (int i = 0; i < 8; ++i) hreg[i] = *(const float4*)(h + 4*sj + 64*i);
        {
            const float* trow = tape + ss * TSTRIDE;
            float acc = 0.f;
            #pragma unroll
            for (int i = 0; i < 8; ++i) {
                const int k = 4*sj + 64*i;
                float4 tv = *(const float4*)(trow + k);
                acc = fmaf(tv.x, hreg[i].x, acc);
                acc = fmaf(tv.y, hreg[i].y, acc);
                acc = fmaf(tv.z, hreg[i].z, acc);
                acc = fmaf(tv.w, hreg[i].w, acc);
            }
            acc += __shfl_xor(acc, 1);
            acc += __shfl_xor(acc, 2);
            acc += __shfl_xor(acc, 4);
            acc += __shfl_xor(acc, 8);
            if (sj == 0) scores[ss] = acc * SCALE;
        }
        __syncthreads();

        // ---- phase 2: softmax over 64 slots (wave 0 only) ----
        if (wave == 0) {
            const float v = scores[lane];
            float m = v;
            #pragma unroll
            for (int o = 32; o; o >>= 1) m = fmaxf(m, __shfl_xor(m, o));
            const float e = __expf(v - m);
            float s = e;
            #pragma unroll
            for (int o = 32; o; o >>= 1) s += __shfl_xor(s, o);
            attn[lane] = e / s;
        }
        __syncthreads();

        // ---- phase 3: read partials (writes rp; disjoint from phase 4's zm) ----
        {
            const int d = tid & 511, g = tid >> 9;
            const float* tcol = tape + (g * 32) * TSTRIDE + d;
            float acc = 0.f;
            #pragma unroll 8
            for (int s = 0; s < 32; ++s)
                acc = fmaf(attn[g*32 + s], tcol[s * TSTRIDE], acc);
            rp[g][d] = acc;
        }

        // ---- phase 4: zm = W_h . h  (no barrier needed after ph3: disjoint writes) ----
        {
            #pragma unroll 2
            for (int it = 0; it < 8; ++it) {
                const int row = it * 64 + wave * 4 + r4;
                const float* wrow = W_h + (size_t)row * D_SZ;
                float acc = 0.f;
                #pragma unroll
                for (int i = 0; i < 8; ++i) {
                    float4 wv = *(const float4*)(wrow + 4*sj + 64*i);
                    acc = fmaf(wv.x, hreg[i].x, acc);
                    acc = fmaf(wv.y, hreg[i].y, acc);
                    acc = fmaf(wv.z, hreg[i].z, acc);
                    acc = fmaf(wv.w, hreg[i].w, acc);
                }
                acc += __shfl_xor(acc, 1);
                acc += __shfl_xor(acc, 2);
                acc += __shfl_xor(acc, 4);
                acc += __shfl_xor(acc, 8);
                if (sj == 0) zm[row] = acc;
            }
        }
        __syncthreads();

        // ---- phase 5: h_new = tanh(zm + read + xw) ----
        if (tid < D_SZ) {
            const float xw = outb[(size_t)t * D_SZ + tid];
            const float v  = tanhf(zm[tid] + rp[0][tid] + rp[1][tid] + xw);
            hn[tid] = v;
            outb[(size_t)t * D_SZ + tid] = v;
        }
        __syncthreads();

        // ---- phase 6: tape[t%64] = W_write . h_new ----
        {
            const int slot = t & (NSLOT - 1);
            float4 hr[8];
            #pragma unroll
            for (int i = 0; i < 8; ++i) hr[i] = *(const float4*)(hn + 4*sj + 64*i);
            #pragma unroll 2
            for (int it = 0; it < 8; ++it) {
                const int row = it * 64 + wave * 4 + r4;
                const float* wrow = W_w + (size_t)row * D_SZ;
                float acc = 0.f;
                #pragma unroll
                for (int i = 0; i < 8; ++i) {
                    float4 wv = *(const float4*)(wrow + 4*sj + 64*i);
                    acc = fmaf(wv.x, hr[i].x, acc);
                    acc = fmaf(wv.y, hr[i].y, acc);
                    acc = fmaf(wv.z, hr[i].z, acc);
                    acc = fmaf(wv.w, hr[i].w, acc);
                }
                acc += __shfl_xor(acc, 1);
                acc += __shfl_xor(acc, 2);
                acc += __shfl_xor(acc, 4);
                acc += __shfl_xor(acc, 8);
                if (sj == 0) tape[slot * TSTRIDE + row] = acc;
            }
        }
        cur ^= 1;
        __syncthreads();
    }

    // ---- epilogue: tape_final and last h ----
    float* tout = out + (size_t)B_SZ * T_SZ * D_SZ + (size_t)b * NSLOT * D_SZ;
    for (int i = tid; i < NSLOT * D_SZ; i += 1024) {
        const int s = i >> 9, d = i & 511;
        tout[i] = tape[s * TSTRIDE + d];
    }
    float* lout = out + (size_t)B_SZ * T_SZ * D_SZ + (size_t)B_SZ * NSLOT * D_SZ
                      + (size_t)b * D_SZ;
    if (tid < D_SZ) lout[tid] = hbuf[cur][tid];
}

// ---------------------------------------------------------------------------
extern "C" void kernel_launch(void* const* d_in, const int* in_sizes, int n_in,
                              void* d_out, int out_size, void* d_ws, size_t ws_size,
                              hipStream_t stream)
{
    const float* x_seq   = (const float*)d_in[0];  // [16,4096,512]
    const float* h_tape  = (const float*)d_in[1];  // [16,64,512]
    const float* h_work  = (const float*)d_in[2];  // [16,512]
    const float* W_h     = (const float*)d_in[3];  // [512,512]
    const float* W_x     = (const float*)d_in[4];  // [512,512]
    const float* b_h     = (const float*)d_in[5];  // [512]
    const float* W_write = (const float*)d_in[6];  // [512,512]
    float* out = (float*)d_out;

    // Kernel 1: xw + bias into the h_work_out region of d_out
    dim3 g1(T_SZ * B_SZ / 64, D_SZ / 64);   // (1024, 8)
    xw_gemm_kernel<<<g1, 256, 0, stream>>>(x_seq, W_x, b_h, out);

    // Kernel 2: serial recurrence, one workgroup per batch
    recurrence_kernel<<<B_SZ, 1024, 0, stream>>>(h_tape, h_work, W_h, W_write, out);
}